// Round 14
// baseline (382.765 us; speedup 1.0000x reference)
//
#include <hip/hip_runtime.h>

#define FDIM 64

typedef unsigned short u16;
typedef unsigned int u32;
typedef float v2f __attribute__((ext_vector_type(2)));

__device__ __forceinline__ u16 f2bf(float x) {          // RNE f32->bf16
    unsigned int u = __float_as_uint(x);
    return (u16)((u + 0x7fff + ((u >> 16) & 1)) >> 16);
}
__device__ __forceinline__ float bf2f(u16 h) {
    return __uint_as_float(((unsigned int)h) << 16);
}
// pack 4 f32 -> 4 fp8 e4m3 (OCP on gfx950) in one u32
__device__ __forceinline__ u32 pk_fp8x4(float a, float b, float c, float d) {
    u32 p = __builtin_amdgcn_cvt_pk_fp8_f32(a, b, 0, false);
    p = __builtin_amdgcn_cvt_pk_fp8_f32(c, d, p, true);
    return p;
}

// ==== dense tile: t0/t1[64 rows] = act(ain + bias) @ W (fp8, split halves) ==
// Known-good 52-VGPR structure: A staged to LDS f32, W in LDS.
// Feature halves go to separate arrays (each 3.2 MB -> per-XCD L2 resident).

template <bool BF16IN>
__device__ __forceinline__ void mm_tile64(
    const void* __restrict__ ain, const float* __restrict__ bias, int do_relu,
    u32* __restrict__ t0, u32* __restrict__ t1, int n, int blk,
    float (*__restrict__ As)[FDIM + 1], float* __restrict__ Ws)
{
    int tid = threadIdx.x;
    int r0 = blk * 64;

    #pragma unroll
    for (int i = 0; i < 4; ++i) {
        int idx = tid + 256 * i;
        int r = idx >> 4;
        int kq = idx & 15;
        float4 v = make_float4(0.f, 0.f, 0.f, 0.f);
        int R = r0 + r;
        if (R < n) {
            if (BF16IN) {
                ushort4 h = ((const ushort4*)ain)[(size_t)R * 16 + kq];
                v.x = bf2f(h.x); v.y = bf2f(h.y); v.z = bf2f(h.z); v.w = bf2f(h.w);
            } else {
                v = ((const float4*)ain)[(size_t)R * 16 + kq];
            }
            if (bias != nullptr) {
                float4 b = ((const float4*)bias)[kq];
                v.x += b.x; v.y += b.y; v.z += b.z; v.w += b.w;
            }
            if (do_relu) {
                v.x = fmaxf(v.x, 0.f); v.y = fmaxf(v.y, 0.f);
                v.z = fmaxf(v.z, 0.f); v.w = fmaxf(v.w, 0.f);
            }
        }
        As[r][kq * 4 + 0] = v.x;
        As[r][kq * 4 + 1] = v.y;
        As[r][kq * 4 + 2] = v.z;
        As[r][kq * 4 + 3] = v.w;
    }
    __syncthreads();

    int rq = tid >> 4;   // rows rq*4..+3
    int cq = tid & 15;   // cols cq*4..+3
    float acc[4][4];
    #pragma unroll
    for (int i = 0; i < 4; ++i)
        #pragma unroll
        for (int j = 0; j < 4; ++j) acc[i][j] = 0.f;

    const float4* Ws4 = (const float4*)Ws;
    #pragma unroll 4
    for (int k = 0; k < FDIM; ++k) {
        float4 w = Ws4[k * 16 + cq];
        float a[4];
        #pragma unroll
        for (int i = 0; i < 4; ++i) a[i] = As[rq * 4 + i][k];
        #pragma unroll
        for (int i = 0; i < 4; ++i) {
            acc[i][0] = fmaf(a[i], w.x, acc[i][0]);
            acc[i][1] = fmaf(a[i], w.y, acc[i][1]);
            acc[i][2] = fmaf(a[i], w.z, acc[i][2]);
            acc[i][3] = fmaf(a[i], w.w, acc[i][3]);
        }
    }

    u32* th = (cq < 8) ? t0 : t1;
    int co = cq & 7;
    #pragma unroll
    for (int i = 0; i < 4; ++i) {
        int R = r0 + rq * 4 + i;
        if (R < n)
            th[(size_t)R * 8 + co] =
                pk_fp8x4(acc[i][0], acc[i][1], acc[i][2], acc[i][3]);
    }
}

// layers 2/3: A = bf16 agg
__global__ __launch_bounds__(256) void k_matmul_h(
    const u16* __restrict__ ain, const float* __restrict__ Wm,
    const float* __restrict__ bias, u32* __restrict__ t0, u32* __restrict__ t1,
    int n)
{
    __shared__ float As[64][FDIM + 1];
    __shared__ float Ws[FDIM * FDIM];
    int tid = threadIdx.x;
    #pragma unroll
    for (int i = 0; i < 4; ++i)
        ((float4*)Ws)[tid + 256 * i] = ((const float4*)Wm)[tid + 256 * i];
    mm_tile64<true>(ain, bias, 1, t0, t1, n, blockIdx.x, As, Ws);
}

// ===== combined dispatch: matmul1 blocks + XCD-partitioned CSR-fill blocks ==
// Fill: 4 independent edges/iter (load x4 -> atomic x4 -> store x4).

__global__ __launch_bounds__(256) void k_mm_fill(
    const float* __restrict__ x, const float* __restrict__ W1,
    u32* __restrict__ t0, u32* __restrict__ t1,
    const int* __restrict__ src, const int* __restrict__ dst,
    int* __restrict__ cnt, int* __restrict__ csr,
    int n, int E, int cap, int mm_blocks, int fill_chunks)
{
    __shared__ float As[64][FDIM + 1];
    __shared__ float Ws[FDIM * FDIM];

    if ((int)blockIdx.x < mm_blocks) {
        int tid = threadIdx.x;
        #pragma unroll
        for (int i = 0; i < 4; ++i)
            ((float4*)Ws)[tid + 256 * i] = ((const float4*)W1)[tid + 256 * i];
        mm_tile64<false>(x, nullptr, 0, t0, t1, n, blockIdx.x, As, Ws);
        return;
    }
    int gb = blockIdx.x - mm_blocks;
    int part = blockIdx.x & 7;
    int chunk = gb >> 3;
    int psz = n >> 3;
    int lo = psz * part;
    int hi = (part == 7) ? n : lo + psz;
    int per = (E + fill_chunks - 1) / fill_chunks;
    int ebeg = chunk * per;
    int eend = ebeg + per; if (eend > E) eend = E;

    int e = ebeg + (int)threadIdx.x;
    for (; e + 768 < eend; e += 1024) {
        int d0 = __builtin_nontemporal_load(&dst[e]);
        int d1 = __builtin_nontemporal_load(&dst[e + 256]);
        int d2 = __builtin_nontemporal_load(&dst[e + 512]);
        int d3 = __builtin_nontemporal_load(&dst[e + 768]);
        int s0 = __builtin_nontemporal_load(&src[e]);
        int s1 = __builtin_nontemporal_load(&src[e + 256]);
        int s2 = __builtin_nontemporal_load(&src[e + 512]);
        int s3 = __builtin_nontemporal_load(&src[e + 768]);
        bool k0 = (d0 >= lo) && (d0 < hi);
        bool k1 = (d1 >= lo) && (d1 < hi);
        bool k2 = (d2 >= lo) && (d2 < hi);
        bool k3 = (d3 >= lo) && (d3 < hi);
        int p0 = 0, p1 = 0, p2 = 0, p3 = 0;
        if (k0) p0 = atomicAdd(&cnt[d0], 1);
        if (k1) p1 = atomicAdd(&cnt[d1], 1);
        if (k2) p2 = atomicAdd(&cnt[d2], 1);
        if (k3) p3 = atomicAdd(&cnt[d3], 1);
        if (k0 && p0 < cap) csr[(size_t)d0 * cap + p0] = s0;
        if (k1 && p1 < cap) csr[(size_t)d1 * cap + p1] = s1;
        if (k2 && p2 < cap) csr[(size_t)d2 * cap + p2] = s2;
        if (k3 && p3 < cap) csr[(size_t)d3 * cap + p3] = s3;
    }
    for (; e < eend; e += 256) {
        int d = dst[e];
        if (d >= lo && d < hi) {
            int p = atomicAdd(&cnt[d], 1);
            if (p < cap) csr[(size_t)d * cap + p] = src[e];
        }
    }
}

// == aggregate (XCD-pinned feature half): out[i,half] = di*(di*t_i + sum dj*t_j)
// xcd = blockIdx&7: XCDs 0-3 process half 0 (t0), 4-7 half 1 (t1) -> each
// XCD's L2 only caches its 3.2 MB half => gathers are L2 hits after warmup.
// 8 lanes/node (32B half-row), 8 nodes/wave; csr via nt-loads (don't evict t).

__global__ __launch_bounds__(256) void k_aggregate(
    const int* __restrict__ cnt, const int* __restrict__ csr,
    const u32* __restrict__ t0, const u32* __restrict__ t1,
    float* __restrict__ aggf, uint2* __restrict__ aggh,
    int outf32, int n, int cap, int npc)
{
    int tid = threadIdx.x;
    int xcd = blockIdx.x & 7;
    int h = xcd >> 2;
    int cid = ((int)blockIdx.x >> 3) * 4 + (xcd & 3);
    int i0 = cid * npc;
    if (i0 >= n) return;
    int i1 = i0 + npc; if (i1 > n) i1 = n;

    const u32* th = h ? t1 : t0;
    int w = tid >> 6;
    int lane = tid & 63;
    int sub = lane >> 3;      // node within wave (0..7)
    int li = lane & 7;        // u32 within half-row (0..7)
    int nbase = sub << 3;

    for (int i = i0 + w * 8 + sub; i < i1; i += 32) {
        int deg = cnt[i];
        float di = rsqrtf((float)deg + 1.0f);
        int m = deg < cap ? deg : cap;

        u32 sp = th[(size_t)i * 8 + li];
        v2f s0 = __builtin_amdgcn_cvt_pk_f32_fp8(sp, false);
        v2f s1 = __builtin_amdgcn_cvt_pk_f32_fp8(sp, true);
        float4 A0 = make_float4(s0.x * di, s0.y * di, s1.x * di, s1.y * di);
        float4 A1 = make_float4(0.f, 0.f, 0.f, 0.f);

        const int* row = csr + (size_t)i * cap;
        for (int c0 = 0; c0 < m; c0 += 8) {
            int cm = m - c0; if (cm > 8) cm = 8;
            int sv = 0; float dvv = 0.f;
            if (li < cm) {
                sv = __builtin_nontemporal_load(&row[c0 + li]);
                dvv = rsqrtf((float)cnt[sv] + 1.0f);
            }
            if (cm == 8) {
                int jv[8]; float dj[8]; u32 v[8];
                #pragma unroll
                for (int u = 0; u < 8; ++u) {
                    jv[u] = __shfl(sv, nbase + u);
                    dj[u] = __shfl(dvv, nbase + u);
                }
                #pragma unroll
                for (int u = 0; u < 8; ++u) v[u] = th[(size_t)jv[u] * 8 + li];
                #pragma unroll
                for (int u = 0; u < 8; ++u) {
                    v2f x0 = __builtin_amdgcn_cvt_pk_f32_fp8(v[u], false);
                    v2f x1 = __builtin_amdgcn_cvt_pk_f32_fp8(v[u], true);
                    float4* Ap = (u & 1) ? &A1 : &A0;
                    Ap->x = fmaf(x0.x, dj[u], Ap->x);
                    Ap->y = fmaf(x0.y, dj[u], Ap->y);
                    Ap->z = fmaf(x1.x, dj[u], Ap->z);
                    Ap->w = fmaf(x1.y, dj[u], Ap->w);
                }
            } else {
                for (int k = 0; k < cm; ++k) {
                    int j = __shfl(sv, nbase + k);
                    float dj = __shfl(dvv, nbase + k);
                    u32 vv = th[(size_t)j * 8 + li];
                    v2f x0 = __builtin_amdgcn_cvt_pk_f32_fp8(vv, false);
                    v2f x1 = __builtin_amdgcn_cvt_pk_f32_fp8(vv, true);
                    A0.x = fmaf(x0.x, dj, A0.x);
                    A0.y = fmaf(x0.y, dj, A0.y);
                    A0.z = fmaf(x1.x, dj, A0.z);
                    A0.w = fmaf(x1.y, dj, A0.w);
                }
            }
        }

        float4 O;
        O.x = (A0.x + A1.x) * di;
        O.y = (A0.y + A1.y) * di;
        O.z = (A0.z + A1.z) * di;
        O.w = (A0.w + A1.w) * di;
        if (outf32) {
            ((float4*)aggf)[(size_t)i * 16 + h * 8 + li] = O;
        } else {
            uint2 pk;
            pk.x = ((u32)f2bf(O.x)) | (((u32)f2bf(O.y)) << 16);
            pk.y = ((u32)f2bf(O.z)) | (((u32)f2bf(O.w)) << 16);
            aggh[(size_t)i * 16 + h * 8 + li] = pk;
        }
    }
}

// ================= pool =================

__global__ __launch_bounds__(256) void k_pool1(
    const float* __restrict__ agg, const int* __restrict__ batch,
    float* __restrict__ partial, int n)
{
    int g = blockIdx.x >> 3;
    int part = blockIdx.x & 7;
    int tid = threadIdx.x;

    int lo = 0, hi = n;
    while (lo < hi) { int mid = (lo + hi) >> 1; if (batch[mid] < g) lo = mid + 1; else hi = mid; }
    int start = lo;
    hi = n;
    while (lo < hi) { int mid = (lo + hi) >> 1; if (batch[mid] <= g) lo = mid + 1; else hi = mid; }
    int end = lo;

    int f = tid & 63, r = tid >> 6;
    float s = 0.f;
    for (int i = start + part * 4 + r; i < end; i += 32)
        s += agg[(size_t)i * 64 + f];

    __shared__ float red[4][64];
    red[r][f] = s;
    __syncthreads();
    if (tid < 64)
        partial[((size_t)g * 8 + part) * 64 + tid] =
            red[0][tid] + red[1][tid] + red[2][tid] + red[3][tid];
}

__global__ __launch_bounds__(64) void k_pool2(
    const float* __restrict__ partial, const int* __restrict__ batch,
    const float* __restrict__ b3, const float* __restrict__ Wlin,
    const float* __restrict__ blin, float* __restrict__ out,
    int n, int fout)
{
    int g = blockIdx.x;
    int tid = threadIdx.x;

    int lo = 0, hi = n;
    while (lo < hi) { int mid = (lo + hi) >> 1; if (batch[mid] < g) lo = mid + 1; else hi = mid; }
    int start = lo;
    hi = n;
    while (lo < hi) { int mid = (lo + hi) >> 1; if (batch[mid] <= g) lo = mid + 1; else hi = mid; }
    int cnt = lo - start;

    __shared__ float pooled[64];
    float v = 0.f;
    #pragma unroll
    for (int p = 0; p < 8; ++p) v += partial[((size_t)g * 8 + p) * 64 + tid];
    pooled[tid] = (cnt > 0) ? (v / (float)cnt + b3[tid]) : 0.f;
    __syncthreads();
    if (tid < fout) {
        float o = blin[tid];
        for (int k = 0; k < 64; ++k) o += pooled[k] * Wlin[k * fout + tid];
        out[(size_t)g * fout + tid] = o;
    }
}

// ================= launcher =================

extern "C" void kernel_launch(void* const* d_in, const int* in_sizes, int n_in,
                              void* d_out, int out_size, void* d_ws, size_t ws_size,
                              hipStream_t stream) {
    const float* x     = (const float*)d_in[0];
    const int*   ei    = (const int*)d_in[1];
    const int*   batch = (const int*)d_in[2];
    const float* W1 = (const float*)d_in[3];
    const float* b1 = (const float*)d_in[4];
    const float* W2 = (const float*)d_in[5];
    const float* b2 = (const float*)d_in[6];
    const float* W3 = (const float*)d_in[7];
    const float* b3 = (const float*)d_in[8];
    const float* Wl = (const float*)d_in[9];
    const float* bl = (const float*)d_in[10];

    int n = in_sizes[0] / 64;
    int E = in_sizes[1] / 2;
    int fout = in_sizes[10];
    int ngraphs = out_size / fout;

    const int* srcp = ei;
    const int* dstp = ei + E;

    // ws layout: agg | t0 fp8-half | t1 fp8-half | partial | cnt | csr
    float* ws   = (float*)d_ws;
    float* agg  = ws;                              // n*64 f32 (also holds bf16 agg)
    u32*   t0   = (u32*)(agg + (size_t)n * 64);    // n*8 u32 (feats 0..31 fp8)
    u32*   t1   = t0 + (size_t)n * 8;              // n*8 u32 (feats 32..63 fp8)
    float* partial = (float*)(t1 + (size_t)n * 8); // 64*8*64
    int* cnt    = (int*)(partial + 64 * 8 * 64);   // n
    int* csr    = cnt + n;                         // n*cap

    size_t fixed = (size_t)n * 64 * 4 + (size_t)n * 16 * 4 +
                   64 * 8 * 64 * 4 + (size_t)n * 4;
    int cap = 64;
    while (cap > 32 && fixed + (size_t)n * cap * 4 > ws_size) cap -= 8;

    int mm_blocks = (((n + 63) / 64 + 7) / 8) * 8;   // multiple of 8
    int fill_chunks = 128;                            // 8 parts x 128 = 1024 blocks
    int nchunks = 1024;                               // node chunks per half
    int npc = (n + nchunks - 1) / nchunks;
    int ag_grid = 8 * (nchunks / 4);                  // 2048 blocks

    hipMemsetAsync(cnt, 0, (size_t)n * sizeof(int), stream);
    // t1 = x @ W1 (fp8 halves) + CSR build, overlapped in one dispatch
    k_mm_fill<<<mm_blocks + 8 * fill_chunks, 256, 0, stream>>>(
        x, W1, t0, t1, srcp, dstp, cnt, csr, n, E, cap, mm_blocks, fill_chunks);

    // layer 1 aggregate -> bf16 agg (in-place)
    k_aggregate<<<ag_grid, 256, 0, stream>>>(cnt, csr, t0, t1, agg, (uint2*)agg, 0, n, cap, npc);
    // layer 2
    k_matmul_h<<<mm_blocks, 256, 0, stream>>>((const u16*)agg, W2, b1, t0, t1, n);
    k_aggregate<<<ag_grid, 256, 0, stream>>>(cnt, csr, t0, t1, agg, (uint2*)agg, 0, n, cap, npc);
    // layer 3
    k_matmul_h<<<mm_blocks, 256, 0, stream>>>((const u16*)agg, W3, b2, t0, t1, n);
    k_aggregate<<<ag_grid, 256, 0, stream>>>(cnt, csr, t0, t1, agg, (uint2*)agg, 1, n, cap, npc);

    // pool + linear
    k_pool1<<<ngraphs * 8, 256, 0, stream>>>(agg, batch, partial, n);
    k_pool2<<<ngraphs, 64, 0, stream>>>(partial, batch, b3, Wl, bl, (float*)d_out, n, fout);
}

// Round 15
// 288.229 us; speedup vs baseline: 1.3280x; 1.3280x over previous
//
#include <hip/hip_runtime.h>

#define FDIM 64

typedef unsigned short u16;
typedef unsigned int u32;
typedef float v2f __attribute__((ext_vector_type(2)));

__device__ __forceinline__ u16 f2bf(float x) {          // RNE f32->bf16
    unsigned int u = __float_as_uint(x);
    return (u16)((u + 0x7fff + ((u >> 16) & 1)) >> 16);
}
__device__ __forceinline__ float bf2f(u16 h) {
    return __uint_as_float(((unsigned int)h) << 16);
}
// pack 4 f32 -> 4 fp8 e4m3 (OCP on gfx950) in one u32
__device__ __forceinline__ u32 pk_fp8x4(float a, float b, float c, float d) {
    u32 p = __builtin_amdgcn_cvt_pk_fp8_f32(a, b, 0, false);
    p = __builtin_amdgcn_cvt_pk_fp8_f32(c, d, p, true);
    return p;
}

// ========= dense tile: t[64 rows] = act(ain + bias) @ W  (fp8 out) =========
// Known-good 52-VGPR structure: A staged to LDS f32, W in LDS.

template <bool BF16IN>
__device__ __forceinline__ void mm_tile64(
    const void* __restrict__ ain, const float* __restrict__ bias, int do_relu,
    u32* __restrict__ t, int n, int blk,
    float (*__restrict__ As)[FDIM + 1], float* __restrict__ Ws)
{
    int tid = threadIdx.x;
    int r0 = blk * 64;

    #pragma unroll
    for (int i = 0; i < 4; ++i) {
        int idx = tid + 256 * i;
        int r = idx >> 4;
        int kq = idx & 15;
        float4 v = make_float4(0.f, 0.f, 0.f, 0.f);
        int R = r0 + r;
        if (R < n) {
            if (BF16IN) {
                ushort4 h = ((const ushort4*)ain)[(size_t)R * 16 + kq];
                v.x = bf2f(h.x); v.y = bf2f(h.y); v.z = bf2f(h.z); v.w = bf2f(h.w);
            } else {
                v = ((const float4*)ain)[(size_t)R * 16 + kq];
            }
            if (bias != nullptr) {
                float4 b = ((const float4*)bias)[kq];
                v.x += b.x; v.y += b.y; v.z += b.z; v.w += b.w;
            }
            if (do_relu) {
                v.x = fmaxf(v.x, 0.f); v.y = fmaxf(v.y, 0.f);
                v.z = fmaxf(v.z, 0.f); v.w = fmaxf(v.w, 0.f);
            }
        }
        As[r][kq * 4 + 0] = v.x;
        As[r][kq * 4 + 1] = v.y;
        As[r][kq * 4 + 2] = v.z;
        As[r][kq * 4 + 3] = v.w;
    }
    __syncthreads();

    int rq = tid >> 4;   // rows rq*4..+3
    int cq = tid & 15;   // cols cq*4..+3
    float acc[4][4];
    #pragma unroll
    for (int i = 0; i < 4; ++i)
        #pragma unroll
        for (int j = 0; j < 4; ++j) acc[i][j] = 0.f;

    const float4* Ws4 = (const float4*)Ws;
    #pragma unroll 4
    for (int k = 0; k < FDIM; ++k) {
        float4 w = Ws4[k * 16 + cq];
        float a[4];
        #pragma unroll
        for (int i = 0; i < 4; ++i) a[i] = As[rq * 4 + i][k];
        #pragma unroll
        for (int i = 0; i < 4; ++i) {
            acc[i][0] = fmaf(a[i], w.x, acc[i][0]);
            acc[i][1] = fmaf(a[i], w.y, acc[i][1]);
            acc[i][2] = fmaf(a[i], w.z, acc[i][2]);
            acc[i][3] = fmaf(a[i], w.w, acc[i][3]);
        }
    }

    #pragma unroll
    for (int i = 0; i < 4; ++i) {
        int R = r0 + rq * 4 + i;
        if (R < n)
            t[(size_t)R * 16 + cq] =
                pk_fp8x4(acc[i][0], acc[i][1], acc[i][2], acc[i][3]);
    }
}

// layers 2/3: A = bf16 agg
__global__ __launch_bounds__(256) void k_matmul_h(
    const u16* __restrict__ ain, const float* __restrict__ Wm,
    const float* __restrict__ bias, u32* __restrict__ t, int n)
{
    __shared__ float As[64][FDIM + 1];
    __shared__ float Ws[FDIM * FDIM];
    int tid = threadIdx.x;
    #pragma unroll
    for (int i = 0; i < 4; ++i)
        ((float4*)Ws)[tid + 256 * i] = ((const float4*)Wm)[tid + 256 * i];
    mm_tile64<true>(ain, bias, 1, t, n, blockIdx.x, As, Ws);
}

// ===== combined dispatch: matmul1 blocks + XCD-partitioned CSR-fill blocks ==
// Fill: 8 independent edges/iter (load x8 -> atomic x8 -> store x8) for
// 8 device-scope RMWs in flight per thread.

__global__ __launch_bounds__(256) void k_mm_fill(
    const float* __restrict__ x, const float* __restrict__ W1,
    u32* __restrict__ t,
    const int* __restrict__ src, const int* __restrict__ dst,
    int* __restrict__ cnt, int* __restrict__ csr,
    int n, int E, int cap, int mm_blocks, int fill_chunks)
{
    __shared__ float As[64][FDIM + 1];
    __shared__ float Ws[FDIM * FDIM];

    if ((int)blockIdx.x < mm_blocks) {
        int tid = threadIdx.x;
        #pragma unroll
        for (int i = 0; i < 4; ++i)
            ((float4*)Ws)[tid + 256 * i] = ((const float4*)W1)[tid + 256 * i];
        mm_tile64<false>(x, nullptr, 0, t, n, blockIdx.x, As, Ws);
        return;
    }
    int gb = blockIdx.x - mm_blocks;
    int part = blockIdx.x & 7;
    int chunk = gb >> 3;
    int psz = n >> 3;
    int lo = psz * part;
    int hi = (part == 7) ? n : lo + psz;
    int per = (E + fill_chunks - 1) / fill_chunks;
    int ebeg = chunk * per;
    int eend = ebeg + per; if (eend > E) eend = E;

    int e = ebeg + (int)threadIdx.x;
    for (; e + 1792 < eend; e += 2048) {
        int d[8], s[8], p[8];
        bool kk[8];
        #pragma unroll
        for (int u = 0; u < 8; ++u) d[u] = __builtin_nontemporal_load(&dst[e + 256 * u]);
        #pragma unroll
        for (int u = 0; u < 8; ++u) s[u] = __builtin_nontemporal_load(&src[e + 256 * u]);
        #pragma unroll
        for (int u = 0; u < 8; ++u) kk[u] = (d[u] >= lo) && (d[u] < hi);
        #pragma unroll
        for (int u = 0; u < 8; ++u) { p[u] = 0; if (kk[u]) p[u] = atomicAdd(&cnt[d[u]], 1); }
        #pragma unroll
        for (int u = 0; u < 8; ++u)
            if (kk[u] && p[u] < cap) csr[(size_t)d[u] * cap + p[u]] = s[u];
    }
    for (; e < eend; e += 256) {
        int d = dst[e];
        if (d >= lo && d < hi) {
            int p = atomicAdd(&cnt[d], 1);
            if (p < cap) csr[(size_t)d * cap + p] = src[e];
        }
    }
}

// == aggregate: out[i] = di*(di*t_i + sum_j dj*t_j);  di = rsqrt(deg_i+1) ==
// 4 nodes per wave, 16-lane group per node; t is fp8: one row gather =
// 16 lanes x 4 B = 64 B = ONE cache line. csr preloads are nt (keep t in L2).
// Output: packed bf16 (all layers; pool reads bf16).

__global__ __launch_bounds__(256) void k_aggregate(
    const int* __restrict__ cnt, const int* __restrict__ csr,
    const u32* __restrict__ t, uint2* __restrict__ aggh, int n, int cap)
{
    int tid = threadIdx.x;
    long long gw = ((long long)blockIdx.x * 256 + tid) >> 6;
    int lane = tid & 63;
    int sub = lane >> 4;      // node within wave (0..3)
    int li  = lane & 15;      // u32 index within fp8 row (0..15) = feats li*4..+3
    long long il = gw * 4 + sub;
    if (il >= n) return;
    int i = (int)il;

    int deg = cnt[i];
    float di = rsqrtf((float)deg + 1.0f);
    int m = deg < cap ? deg : cap;

    u32 sp = t[(size_t)i * 16 + li];
    v2f s0 = __builtin_amdgcn_cvt_pk_f32_fp8(sp, false);
    v2f s1 = __builtin_amdgcn_cvt_pk_f32_fp8(sp, true);
    float4 A0 = make_float4(s0.x * di, s0.y * di, s1.x * di, s1.y * di);
    float4 A1 = make_float4(0.f, 0.f, 0.f, 0.f);
    float4 A2 = make_float4(0.f, 0.f, 0.f, 0.f);
    float4 A3 = make_float4(0.f, 0.f, 0.f, 0.f);

    const int* row = csr + (size_t)i * cap;
    int nbase = sub << 4;

    for (int c0 = 0; c0 < m; c0 += 16) {
        int cm = m - c0; if (cm > 16) cm = 16;
        int sv = 0; float dvv = 0.f;
        if (li < cm) {
            sv = __builtin_nontemporal_load(&row[c0 + li]);
            dvv = rsqrtf((float)cnt[sv] + 1.0f);
        }
        int k = 0;
        for (; k + 8 <= cm; k += 8) {
            int jv[8]; float dj[8]; u32 v[8];
            #pragma unroll
            for (int u = 0; u < 8; ++u) {
                jv[u] = __shfl(sv, nbase + k + u);
                dj[u] = __shfl(dvv, nbase + k + u);
            }
            #pragma unroll
            for (int u = 0; u < 8; ++u) v[u] = t[(size_t)jv[u] * 16 + li];
            #pragma unroll
            for (int u = 0; u < 8; ++u) {
                v2f x0 = __builtin_amdgcn_cvt_pk_f32_fp8(v[u], false);
                v2f x1 = __builtin_amdgcn_cvt_pk_f32_fp8(v[u], true);
                float4* Ap = (u & 3) == 0 ? &A0 : (u & 3) == 1 ? &A1 :
                             (u & 3) == 2 ? &A2 : &A3;
                Ap->x = fmaf(x0.x, dj[u], Ap->x);
                Ap->y = fmaf(x0.y, dj[u], Ap->y);
                Ap->z = fmaf(x1.x, dj[u], Ap->z);
                Ap->w = fmaf(x1.y, dj[u], Ap->w);
            }
        }
        if (k + 4 <= cm) {
            int jv[4]; float dj[4]; u32 v[4];
            #pragma unroll
            for (int u = 0; u < 4; ++u) {
                jv[u] = __shfl(sv, nbase + k + u);
                dj[u] = __shfl(dvv, nbase + k + u);
            }
            #pragma unroll
            for (int u = 0; u < 4; ++u) v[u] = t[(size_t)jv[u] * 16 + li];
            #pragma unroll
            for (int u = 0; u < 4; ++u) {
                v2f x0 = __builtin_amdgcn_cvt_pk_f32_fp8(v[u], false);
                v2f x1 = __builtin_amdgcn_cvt_pk_f32_fp8(v[u], true);
                float4* Ap = u == 0 ? &A0 : u == 1 ? &A1 : u == 2 ? &A2 : &A3;
                Ap->x = fmaf(x0.x, dj[u], Ap->x);
                Ap->y = fmaf(x0.y, dj[u], Ap->y);
                Ap->z = fmaf(x1.x, dj[u], Ap->z);
                Ap->w = fmaf(x1.y, dj[u], Ap->w);
            }
            k += 4;
        }
        for (; k < cm; ++k) {
            int j = __shfl(sv, nbase + k);
            float dj = __shfl(dvv, nbase + k);
            u32 vv = t[(size_t)j * 16 + li];
            v2f x0 = __builtin_amdgcn_cvt_pk_f32_fp8(vv, false);
            v2f x1 = __builtin_amdgcn_cvt_pk_f32_fp8(vv, true);
            A0.x = fmaf(x0.x, dj, A0.x);
            A0.y = fmaf(x0.y, dj, A0.y);
            A0.z = fmaf(x1.x, dj, A0.z);
            A0.w = fmaf(x1.y, dj, A0.w);
        }
    }

    float4 O;
    O.x = ((A0.x + A1.x) + (A2.x + A3.x)) * di;
    O.y = ((A0.y + A1.y) + (A2.y + A3.y)) * di;
    O.z = ((A0.z + A1.z) + (A2.z + A3.z)) * di;
    O.w = ((A0.w + A1.w) + (A2.w + A3.w)) * di;
    uint2 pk;
    pk.x = ((u32)f2bf(O.x)) | (((u32)f2bf(O.y)) << 16);
    pk.y = ((u32)f2bf(O.z)) | (((u32)f2bf(O.w)) << 16);
    aggh[(size_t)i * 16 + li] = pk;
}

// ================= pool (bf16 agg in) =================

__global__ __launch_bounds__(256) void k_pool1(
    const u32* __restrict__ aggh, const int* __restrict__ batch,
    float* __restrict__ partial, int n)
{
    int g = blockIdx.x >> 3;
    int part = blockIdx.x & 7;
    int tid = threadIdx.x;

    int lo = 0, hi = n;
    while (lo < hi) { int mid = (lo + hi) >> 1; if (batch[mid] < g) lo = mid + 1; else hi = mid; }
    int start = lo;
    hi = n;
    while (lo < hi) { int mid = (lo + hi) >> 1; if (batch[mid] <= g) lo = mid + 1; else hi = mid; }
    int end = lo;

    int f2 = tid & 31;        // u32 index = features 2*f2, 2*f2+1
    int r = tid >> 5;         // 8 rows in flight
    float sx = 0.f, sy = 0.f;
    for (int i = start + part * 8 + r; i < end; i += 64) {
        u32 v = aggh[(size_t)i * 32 + f2];
        sx += __uint_as_float(v << 16);
        sy += __uint_as_float(v & 0xffff0000u);
    }

    __shared__ float redx[8][32];
    __shared__ float redy[8][32];
    redx[r][f2] = sx;
    redy[r][f2] = sy;
    __syncthreads();
    if (tid < 32) {
        float vx = 0.f, vy = 0.f;
        #pragma unroll
        for (int q = 0; q < 8; ++q) { vx += redx[q][tid]; vy += redy[q][tid]; }
        partial[((size_t)g * 8 + part) * 64 + 2 * tid + 0] = vx;
        partial[((size_t)g * 8 + part) * 64 + 2 * tid + 1] = vy;
    }
}

__global__ __launch_bounds__(64) void k_pool2(
    const float* __restrict__ partial, const int* __restrict__ batch,
    const float* __restrict__ b3, const float* __restrict__ Wlin,
    const float* __restrict__ blin, float* __restrict__ out,
    int n, int fout)
{
    int g = blockIdx.x;
    int tid = threadIdx.x;

    int lo = 0, hi = n;
    while (lo < hi) { int mid = (lo + hi) >> 1; if (batch[mid] < g) lo = mid + 1; else hi = mid; }
    int start = lo;
    hi = n;
    while (lo < hi) { int mid = (lo + hi) >> 1; if (batch[mid] <= g) lo = mid + 1; else hi = mid; }
    int cnt = lo - start;

    __shared__ float pooled[64];
    float v = 0.f;
    #pragma unroll
    for (int p = 0; p < 8; ++p) v += partial[((size_t)g * 8 + p) * 64 + tid];
    pooled[tid] = (cnt > 0) ? (v / (float)cnt + b3[tid]) : 0.f;
    __syncthreads();
    if (tid < fout) {
        float o = blin[tid];
        for (int k = 0; k < 64; ++k) o += pooled[k] * Wlin[k * fout + tid];
        out[(size_t)g * fout + tid] = o;
    }
}

// ================= launcher =================

extern "C" void kernel_launch(void* const* d_in, const int* in_sizes, int n_in,
                              void* d_out, int out_size, void* d_ws, size_t ws_size,
                              hipStream_t stream) {
    const float* x     = (const float*)d_in[0];
    const int*   ei    = (const int*)d_in[1];
    const int*   batch = (const int*)d_in[2];
    const float* W1 = (const float*)d_in[3];
    const float* b1 = (const float*)d_in[4];
    const float* W2 = (const float*)d_in[5];
    const float* b2 = (const float*)d_in[6];
    const float* W3 = (const float*)d_in[7];
    const float* b3 = (const float*)d_in[8];
    const float* Wl = (const float*)d_in[9];
    const float* bl = (const float*)d_in[10];

    int n = in_sizes[0] / 64;
    int E = in_sizes[1] / 2;
    int fout = in_sizes[10];
    int ngraphs = out_size / fout;

    const int* srcp = ei;
    const int* dstp = ei + E;

    // ws layout: agg bf16 | t fp8 | partial | cnt | csr
    float* ws   = (float*)d_ws;
    u32*   agg  = (u32*)ws;                        // n*32 u32 (bf16 pairs)
    u32*   t    = agg + (size_t)n * 32;            // n*16 u32 (fp8 rows, 64 B)
    float* partial = (float*)(t + (size_t)n * 16); // 64*8*64
    int* cnt    = (int*)(partial + 64 * 8 * 64);   // n
    int* csr    = cnt + n;                         // n*cap

    size_t fixed = (size_t)n * 32 * 4 + (size_t)n * 16 * 4 +
                   64 * 8 * 64 * 4 + (size_t)n * 4;
    int cap = 64;
    while (cap > 32 && fixed + (size_t)n * cap * 4 > ws_size) cap -= 8;

    int nb_ag = (int)((((long long)(n + 3) / 4) * 64 + 255) / 256);
    int mm_blocks = (((n + 63) / 64 + 7) / 8) * 8;   // multiple of 8
    int fill_chunks = 128;                            // 8 parts x 128 = 1024 blocks

    hipMemsetAsync(cnt, 0, (size_t)n * sizeof(int), stream);
    // t1 = x @ W1 (fp8) + CSR build, overlapped in one dispatch
    k_mm_fill<<<mm_blocks + 8 * fill_chunks, 256, 0, stream>>>(
        x, W1, t, srcp, dstp, cnt, csr, n, E, cap, mm_blocks, fill_chunks);

    // layer 1 aggregate -> bf16 agg
    k_aggregate<<<nb_ag, 256, 0, stream>>>(cnt, csr, t, (uint2*)agg, n, cap);
    // layer 2
    k_matmul_h<<<mm_blocks, 256, 0, stream>>>((const u16*)agg, W2, b1, t, n);
    k_aggregate<<<nb_ag, 256, 0, stream>>>(cnt, csr, t, (uint2*)agg, n, cap);
    // layer 3
    k_matmul_h<<<mm_blocks, 256, 0, stream>>>((const u16*)agg, W3, b2, t, n);
    k_aggregate<<<nb_ag, 256, 0, stream>>>(cnt, csr, t, (uint2*)agg, n, cap);

    // pool + linear
    k_pool1<<<ngraphs * 8, 256, 0, stream>>>(agg, batch, partial, n);
    k_pool2<<<ngraphs, 64, 0, stream>>>(partial, batch, b3, Wl, bl, (float*)d_out, n, fout);
}

// Round 16
// 282.132 us; speedup vs baseline: 1.3567x; 1.0216x over previous
//
#include <hip/hip_runtime.h>

#define FDIM 64

typedef unsigned short u16;
typedef unsigned int u32;
typedef float v2f __attribute__((ext_vector_type(2)));

__device__ __forceinline__ u16 f2bf(float x) {          // RNE f32->bf16
    unsigned int u = __float_as_uint(x);
    return (u16)((u + 0x7fff + ((u >> 16) & 1)) >> 16);
}
__device__ __forceinline__ float bf2f(u16 h) {
    return __uint_as_float(((unsigned int)h) << 16);
}
// pack 4 f32 -> 4 fp8 e4m3 (OCP on gfx950) in one u32
__device__ __forceinline__ u32 pk_fp8x4(float a, float b, float c, float d) {
    u32 p = __builtin_amdgcn_cvt_pk_fp8_f32(a, b, 0, false);
    p = __builtin_amdgcn_cvt_pk_fp8_f32(c, d, p, true);
    return p;
}

// ========= dense tile: t[64 rows] = act(ain + bias) @ W  (fp8 out) =========
// Known-good 52-VGPR structure: A staged to LDS f32, W in LDS.

template <bool BF16IN>
__device__ __forceinline__ void mm_tile64(
    const void* __restrict__ ain, const float* __restrict__ bias, int do_relu,
    u32* __restrict__ t, int n, int blk,
    float (*__restrict__ As)[FDIM + 1], float* __restrict__ Ws)
{
    int tid = threadIdx.x;
    int r0 = blk * 64;

    #pragma unroll
    for (int i = 0; i < 4; ++i) {
        int idx = tid + 256 * i;
        int r = idx >> 4;
        int kq = idx & 15;
        float4 v = make_float4(0.f, 0.f, 0.f, 0.f);
        int R = r0 + r;
        if (R < n) {
            if (BF16IN) {
                ushort4 h = ((const ushort4*)ain)[(size_t)R * 16 + kq];
                v.x = bf2f(h.x); v.y = bf2f(h.y); v.z = bf2f(h.z); v.w = bf2f(h.w);
            } else {
                v = ((const float4*)ain)[(size_t)R * 16 + kq];
            }
            if (bias != nullptr) {
                float4 b = ((const float4*)bias)[kq];
                v.x += b.x; v.y += b.y; v.z += b.z; v.w += b.w;
            }
            if (do_relu) {
                v.x = fmaxf(v.x, 0.f); v.y = fmaxf(v.y, 0.f);
                v.z = fmaxf(v.z, 0.f); v.w = fmaxf(v.w, 0.f);
            }
        }
        As[r][kq * 4 + 0] = v.x;
        As[r][kq * 4 + 1] = v.y;
        As[r][kq * 4 + 2] = v.z;
        As[r][kq * 4 + 3] = v.w;
    }
    __syncthreads();

    int rq = tid >> 4;   // rows rq*4..+3
    int cq = tid & 15;   // cols cq*4..+3
    float acc[4][4];
    #pragma unroll
    for (int i = 0; i < 4; ++i)
        #pragma unroll
        for (int j = 0; j < 4; ++j) acc[i][j] = 0.f;

    const float4* Ws4 = (const float4*)Ws;
    #pragma unroll 4
    for (int k = 0; k < FDIM; ++k) {
        float4 w = Ws4[k * 16 + cq];
        float a[4];
        #pragma unroll
        for (int i = 0; i < 4; ++i) a[i] = As[rq * 4 + i][k];
        #pragma unroll
        for (int i = 0; i < 4; ++i) {
            acc[i][0] = fmaf(a[i], w.x, acc[i][0]);
            acc[i][1] = fmaf(a[i], w.y, acc[i][1]);
            acc[i][2] = fmaf(a[i], w.z, acc[i][2]);
            acc[i][3] = fmaf(a[i], w.w, acc[i][3]);
        }
    }

    #pragma unroll
    for (int i = 0; i < 4; ++i) {
        int R = r0 + rq * 4 + i;
        if (R < n)
            t[(size_t)R * 16 + cq] =
                pk_fp8x4(acc[i][0], acc[i][1], acc[i][2], acc[i][3]);
    }
}

// layers 2/3: A = bf16 agg
__global__ __launch_bounds__(256) void k_matmul_h(
    const u16* __restrict__ ain, const float* __restrict__ Wm,
    const float* __restrict__ bias, u32* __restrict__ t, int n)
{
    __shared__ float As[64][FDIM + 1];
    __shared__ float Ws[FDIM * FDIM];
    int tid = threadIdx.x;
    #pragma unroll
    for (int i = 0; i < 4; ++i)
        ((float4*)Ws)[tid + 256 * i] = ((const float4*)Wm)[tid + 256 * i];
    mm_tile64<true>(ain, bias, 1, t, n, blockIdx.x, As, Ws);
}

// ===== combined dispatch: CSR-fill blocks (first) + matmul1 blocks =========
// Fill: UNPARTITIONED grid-stride, 8 truly-independent atomics in flight per
// thread (no dst filter -> no pipeline dilution, no 8x dst re-read).

__global__ __launch_bounds__(256) void k_mm_fill(
    const float* __restrict__ x, const float* __restrict__ W1,
    u32* __restrict__ t,
    const int* __restrict__ src, const int* __restrict__ dst,
    int* __restrict__ cnt, int* __restrict__ csr,
    int n, int E, int cap, int fill_blocks)
{
    __shared__ float As[64][FDIM + 1];
    __shared__ float Ws[FDIM * FDIM];

    if ((int)blockIdx.x < fill_blocks) {
        int stride = fill_blocks * 256;
        int e = blockIdx.x * 256 + threadIdx.x;
        for (; e + 7 * stride < E; e += 8 * stride) {
            int d[8], s[8], p[8];
            #pragma unroll
            for (int u = 0; u < 8; ++u)
                d[u] = __builtin_nontemporal_load(&dst[e + u * stride]);
            #pragma unroll
            for (int u = 0; u < 8; ++u)
                s[u] = __builtin_nontemporal_load(&src[e + u * stride]);
            #pragma unroll
            for (int u = 0; u < 8; ++u) p[u] = atomicAdd(&cnt[d[u]], 1);
            #pragma unroll
            for (int u = 0; u < 8; ++u)
                if (p[u] < cap) csr[(size_t)d[u] * cap + p[u]] = s[u];
        }
        for (; e < E; e += stride) {
            int d = dst[e];
            int p = atomicAdd(&cnt[d], 1);
            if (p < cap) csr[(size_t)d * cap + p] = src[e];
        }
        return;
    }

    int blk = blockIdx.x - fill_blocks;
    int tid = threadIdx.x;
    #pragma unroll
    for (int i = 0; i < 4; ++i)
        ((float4*)Ws)[tid + 256 * i] = ((const float4*)W1)[tid + 256 * i];
    mm_tile64<false>(x, nullptr, 0, t, n, blk, As, Ws);
}

// ======= gather-aggregate body for one node (16-lane group) ================
// returns O = di*(di*t_i + sum_j dj*t_j) for this lane's 4 features.

__device__ __forceinline__ float4 agg_node(
    int i, const int* __restrict__ cnt, const int* __restrict__ csr,
    const u32* __restrict__ t, int cap, int li, int nbase)
{
    int deg = cnt[i];
    float di = rsqrtf((float)deg + 1.0f);
    int m = deg < cap ? deg : cap;

    u32 sp = t[(size_t)i * 16 + li];
    v2f s0 = __builtin_amdgcn_cvt_pk_f32_fp8(sp, false);
    v2f s1 = __builtin_amdgcn_cvt_pk_f32_fp8(sp, true);
    float4 A0 = make_float4(s0.x * di, s0.y * di, s1.x * di, s1.y * di);
    float4 A1 = make_float4(0.f, 0.f, 0.f, 0.f);
    float4 A2 = make_float4(0.f, 0.f, 0.f, 0.f);
    float4 A3 = make_float4(0.f, 0.f, 0.f, 0.f);

    const int* row = csr + (size_t)i * cap;

    for (int c0 = 0; c0 < m; c0 += 16) {
        int cm = m - c0; if (cm > 16) cm = 16;
        int sv = 0; float dvv = 0.f;
        if (li < cm) {
            sv = __builtin_nontemporal_load(&row[c0 + li]);
            dvv = rsqrtf((float)cnt[sv] + 1.0f);
        }
        int k = 0;
        for (; k + 8 <= cm; k += 8) {
            int jv[8]; float dj[8]; u32 v[8];
            #pragma unroll
            for (int u = 0; u < 8; ++u) {
                jv[u] = __shfl(sv, nbase + k + u);
                dj[u] = __shfl(dvv, nbase + k + u);
            }
            #pragma unroll
            for (int u = 0; u < 8; ++u) v[u] = t[(size_t)jv[u] * 16 + li];
            #pragma unroll
            for (int u = 0; u < 8; ++u) {
                v2f x0 = __builtin_amdgcn_cvt_pk_f32_fp8(v[u], false);
                v2f x1 = __builtin_amdgcn_cvt_pk_f32_fp8(v[u], true);
                float4* Ap = (u & 3) == 0 ? &A0 : (u & 3) == 1 ? &A1 :
                             (u & 3) == 2 ? &A2 : &A3;
                Ap->x = fmaf(x0.x, dj[u], Ap->x);
                Ap->y = fmaf(x0.y, dj[u], Ap->y);
                Ap->z = fmaf(x1.x, dj[u], Ap->z);
                Ap->w = fmaf(x1.y, dj[u], Ap->w);
            }
        }
        if (k + 4 <= cm) {
            int jv[4]; float dj[4]; u32 v[4];
            #pragma unroll
            for (int u = 0; u < 4; ++u) {
                jv[u] = __shfl(sv, nbase + k + u);
                dj[u] = __shfl(dvv, nbase + k + u);
            }
            #pragma unroll
            for (int u = 0; u < 4; ++u) v[u] = t[(size_t)jv[u] * 16 + li];
            #pragma unroll
            for (int u = 0; u < 4; ++u) {
                v2f x0 = __builtin_amdgcn_cvt_pk_f32_fp8(v[u], false);
                v2f x1 = __builtin_amdgcn_cvt_pk_f32_fp8(v[u], true);
                float4* Ap = u == 0 ? &A0 : u == 1 ? &A1 : u == 2 ? &A2 : &A3;
                Ap->x = fmaf(x0.x, dj[u], Ap->x);
                Ap->y = fmaf(x0.y, dj[u], Ap->y);
                Ap->z = fmaf(x1.x, dj[u], Ap->z);
                Ap->w = fmaf(x1.y, dj[u], Ap->w);
            }
            k += 4;
        }
        for (; k < cm; ++k) {
            int j = __shfl(sv, nbase + k);
            float dj = __shfl(dvv, nbase + k);
            u32 vv = t[(size_t)j * 16 + li];
            v2f x0 = __builtin_amdgcn_cvt_pk_f32_fp8(vv, false);
            v2f x1 = __builtin_amdgcn_cvt_pk_f32_fp8(vv, true);
            A0.x = fmaf(x0.x, dj, A0.x);
            A0.y = fmaf(x0.y, dj, A0.y);
            A0.z = fmaf(x1.x, dj, A0.z);
            A0.w = fmaf(x1.y, dj, A0.w);
        }
    }

    float4 O;
    O.x = ((A0.x + A1.x) + (A2.x + A3.x)) * di;
    O.y = ((A0.y + A1.y) + (A2.y + A3.y)) * di;
    O.z = ((A0.z + A1.z) + (A2.z + A3.z)) * di;
    O.w = ((A0.w + A1.w) + (A2.w + A3.w)) * di;
    return O;
}

// == aggregate (layers 1-2): bf16 out, 4 nodes/wave, 16-lane groups ==

__global__ __launch_bounds__(256) void k_aggregate(
    const int* __restrict__ cnt, const int* __restrict__ csr,
    const u32* __restrict__ t, uint2* __restrict__ aggh, int n, int cap)
{
    int tid = threadIdx.x;
    long long gw = ((long long)blockIdx.x * 256 + tid) >> 6;
    int lane = tid & 63;
    int sub = lane >> 4;
    int li  = lane & 15;
    long long il = gw * 4 + sub;
    if (il >= n) return;
    int i = (int)il;

    float4 O = agg_node(i, cnt, csr, t, cap, li, sub << 4);
    uint2 pk;
    pk.x = ((u32)f2bf(O.x)) | (((u32)f2bf(O.y)) << 16);
    pk.y = ((u32)f2bf(O.z)) | (((u32)f2bf(O.w)) << 16);
    aggh[(size_t)i * 16 + li] = pk;
}

// == layer-3 aggregate fused with pool: block = (graph, part); each 16-lane
// group aggregates its nodes and keeps the running feature-sum in registers;
// one partial row per block. No agg3 write, no pool1 pass.

__global__ __launch_bounds__(256) void k_agg_pool(
    const int* __restrict__ cnt, const int* __restrict__ csr,
    const u32* __restrict__ t, const int* __restrict__ batch,
    float* __restrict__ partial, int n, int cap, int npart)
{
    int g = blockIdx.x / npart;
    int part = blockIdx.x - g * npart;
    int tid = threadIdx.x;

    int lo = 0, hi = n;
    while (lo < hi) { int mid = (lo + hi) >> 1; if (batch[mid] < g) lo = mid + 1; else hi = mid; }
    int start = lo;
    hi = n;
    while (lo < hi) { int mid = (lo + hi) >> 1; if (batch[mid] <= g) lo = mid + 1; else hi = mid; }
    int end = lo;

    int group = tid >> 4;     // 0..15
    int li = tid & 15;
    int lane = tid & 63;
    int nbase = (lane >> 4) << 4;

    float4 acc = make_float4(0.f, 0.f, 0.f, 0.f);
    for (int i = start + part * 16 + group; i < end; i += npart * 16) {
        float4 O = agg_node(i, cnt, csr, t, cap, li, nbase);
        acc.x += O.x; acc.y += O.y; acc.z += O.z; acc.w += O.w;
    }

    __shared__ float4 red[16][16];
    red[group][li] = acc;
    __syncthreads();
    if (tid < 16) {
        float4 s = make_float4(0.f, 0.f, 0.f, 0.f);
        #pragma unroll
        for (int q = 0; q < 16; ++q) {
            s.x += red[q][tid].x; s.y += red[q][tid].y;
            s.z += red[q][tid].z; s.w += red[q][tid].w;
        }
        ((float4*)partial)[((size_t)g * npart + part) * 16 + tid] = s;
    }
}

__global__ __launch_bounds__(64) void k_pool2(
    const float* __restrict__ partial, const int* __restrict__ batch,
    const float* __restrict__ b3, const float* __restrict__ Wlin,
    const float* __restrict__ blin, float* __restrict__ out,
    int n, int fout, int npart)
{
    int g = blockIdx.x;
    int tid = threadIdx.x;

    int lo = 0, hi = n;
    while (lo < hi) { int mid = (lo + hi) >> 1; if (batch[mid] < g) lo = mid + 1; else hi = mid; }
    int start = lo;
    hi = n;
    while (lo < hi) { int mid = (lo + hi) >> 1; if (batch[mid] <= g) lo = mid + 1; else hi = mid; }
    int cnt = lo - start;

    __shared__ float pooled[64];
    float v = 0.f;
    for (int p = 0; p < npart; ++p)
        v += partial[((size_t)g * npart + p) * 64 + tid];
    pooled[tid] = (cnt > 0) ? (v / (float)cnt + b3[tid]) : 0.f;
    __syncthreads();
    if (tid < fout) {
        float o = blin[tid];
        for (int k = 0; k < 64; ++k) o += pooled[k] * Wlin[k * fout + tid];
        out[(size_t)g * fout + tid] = o;
    }
}

// ================= launcher =================

extern "C" void kernel_launch(void* const* d_in, const int* in_sizes, int n_in,
                              void* d_out, int out_size, void* d_ws, size_t ws_size,
                              hipStream_t stream) {
    const float* x     = (const float*)d_in[0];
    const int*   ei    = (const int*)d_in[1];
    const int*   batch = (const int*)d_in[2];
    const float* W1 = (const float*)d_in[3];
    const float* b1 = (const float*)d_in[4];
    const float* W2 = (const float*)d_in[5];
    const float* b2 = (const float*)d_in[6];
    const float* W3 = (const float*)d_in[7];
    const float* b3 = (const float*)d_in[8];
    const float* Wl = (const float*)d_in[9];
    const float* bl = (const float*)d_in[10];

    int n = in_sizes[0] / 64;
    int E = in_sizes[1] / 2;
    int fout = in_sizes[10];
    int ngraphs = out_size / fout;

    const int* srcp = ei;
    const int* dstp = ei + E;

    const int npart = 16;

    // ws layout: agg bf16 | t fp8 | partial | cnt | csr
    float* ws   = (float*)d_ws;
    u32*   agg  = (u32*)ws;                          // n*32 u32 (bf16 pairs)
    u32*   t    = agg + (size_t)n * 32;              // n*16 u32 (fp8 rows)
    float* partial = (float*)(t + (size_t)n * 16);   // 64*16*64
    int* cnt    = (int*)(partial + 64 * npart * 64); // n
    int* csr    = cnt + n;                           // n*cap

    size_t fixed = (size_t)n * 32 * 4 + (size_t)n * 16 * 4 +
                   64 * npart * 64 * 4 + (size_t)n * 4;
    int cap = 64;
    while (cap > 32 && fixed + (size_t)n * cap * 4 > ws_size) cap -= 8;

    int nb_ag = (int)((((long long)(n + 3) / 4) * 64 + 255) / 256);
    int mm_blocks = (n + 63) / 64;
    int fill_blocks = 256;

    hipMemsetAsync(cnt, 0, (size_t)n * sizeof(int), stream);
    // CSR build (unpartitioned, 8-deep) + t1 = x @ W1 (fp8), one dispatch
    k_mm_fill<<<fill_blocks + mm_blocks, 256, 0, stream>>>(
        x, W1, t, srcp, dstp, cnt, csr, n, E, cap, fill_blocks);

    // layer 1 aggregate -> bf16 agg
    k_aggregate<<<nb_ag, 256, 0, stream>>>(cnt, csr, t, (uint2*)agg, n, cap);
    // layer 2
    k_matmul_h<<<mm_blocks, 256, 0, stream>>>((const u16*)agg, W2, b1, t, n);
    k_aggregate<<<nb_ag, 256, 0, stream>>>(cnt, csr, t, (uint2*)agg, n, cap);
    // layer 3
    k_matmul_h<<<mm_blocks, 256, 0, stream>>>((const u16*)agg, W3, b2, t, n);
    // layer-3 aggregate fused with pool partial-sum
    k_agg_pool<<<ngraphs * npart, 256, 0, stream>>>(cnt, csr, t, batch,
                                                    partial, n, cap, npart);
    k_pool2<<<ngraphs, 64, 0, stream>>>(partial, batch, b3, Wl, bl,
                                        (float*)d_out, n, fout, npart);
}

// Round 17
// 270.543 us; speedup vs baseline: 1.4148x; 1.0428x over previous
//
#include <hip/hip_runtime.h>

#define FDIM 64

typedef unsigned short u16;
typedef unsigned int u32;
typedef float v2f __attribute__((ext_vector_type(2)));

__device__ __forceinline__ u16 f2bf(float x) {          // RNE f32->bf16
    unsigned int u = __float_as_uint(x);
    return (u16)((u + 0x7fff + ((u >> 16) & 1)) >> 16);
}
__device__ __forceinline__ float bf2f(u16 h) {
    return __uint_as_float(((unsigned int)h) << 16);
}
// pack 4 f32 -> 4 fp8 e4m3 (OCP on gfx950) in one u32
__device__ __forceinline__ u32 pk_fp8x4(float a, float b, float c, float d) {
    u32 p = __builtin_amdgcn_cvt_pk_fp8_f32(a, b, 0, false);
    p = __builtin_amdgcn_cvt_pk_fp8_f32(c, d, p, true);
    return p;
}

// ========= dense tile: t[64 rows] = act(ain + bias) @ W  (fp8 out) =========
// Known-good 52-VGPR structure: A staged to LDS f32, W in LDS.

template <bool BF16IN>
__device__ __forceinline__ void mm_tile64(
    const void* __restrict__ ain, const float* __restrict__ bias, int do_relu,
    u32* __restrict__ t, int n, int blk,
    float (*__restrict__ As)[FDIM + 1], float* __restrict__ Ws)
{
    int tid = threadIdx.x;
    int r0 = blk * 64;

    #pragma unroll
    for (int i = 0; i < 4; ++i) {
        int idx = tid + 256 * i;
        int r = idx >> 4;
        int kq = idx & 15;
        float4 v = make_float4(0.f, 0.f, 0.f, 0.f);
        int R = r0 + r;
        if (R < n) {
            if (BF16IN) {
                ushort4 h = ((const ushort4*)ain)[(size_t)R * 16 + kq];
                v.x = bf2f(h.x); v.y = bf2f(h.y); v.z = bf2f(h.z); v.w = bf2f(h.w);
            } else {
                v = ((const float4*)ain)[(size_t)R * 16 + kq];
            }
            if (bias != nullptr) {
                float4 b = ((const float4*)bias)[kq];
                v.x += b.x; v.y += b.y; v.z += b.z; v.w += b.w;
            }
            if (do_relu) {
                v.x = fmaxf(v.x, 0.f); v.y = fmaxf(v.y, 0.f);
                v.z = fmaxf(v.z, 0.f); v.w = fmaxf(v.w, 0.f);
            }
        }
        As[r][kq * 4 + 0] = v.x;
        As[r][kq * 4 + 1] = v.y;
        As[r][kq * 4 + 2] = v.z;
        As[r][kq * 4 + 3] = v.w;
    }
    __syncthreads();

    int rq = tid >> 4;   // rows rq*4..+3
    int cq = tid & 15;   // cols cq*4..+3
    float acc[4][4];
    #pragma unroll
    for (int i = 0; i < 4; ++i)
        #pragma unroll
        for (int j = 0; j < 4; ++j) acc[i][j] = 0.f;

    const float4* Ws4 = (const float4*)Ws;
    #pragma unroll 4
    for (int k = 0; k < FDIM; ++k) {
        float4 w = Ws4[k * 16 + cq];
        float a[4];
        #pragma unroll
        for (int i = 0; i < 4; ++i) a[i] = As[rq * 4 + i][k];
        #pragma unroll
        for (int i = 0; i < 4; ++i) {
            acc[i][0] = fmaf(a[i], w.x, acc[i][0]);
            acc[i][1] = fmaf(a[i], w.y, acc[i][1]);
            acc[i][2] = fmaf(a[i], w.z, acc[i][2]);
            acc[i][3] = fmaf(a[i], w.w, acc[i][3]);
        }
    }

    #pragma unroll
    for (int i = 0; i < 4; ++i) {
        int R = r0 + rq * 4 + i;
        if (R < n)
            t[(size_t)R * 16 + cq] =
                pk_fp8x4(acc[i][0], acc[i][1], acc[i][2], acc[i][3]);
    }
}

// layers 2/3: A = bf16 agg
__global__ __launch_bounds__(256) void k_matmul_h(
    const u16* __restrict__ ain, const float* __restrict__ Wm,
    const float* __restrict__ bias, u32* __restrict__ t, int n)
{
    __shared__ float As[64][FDIM + 1];
    __shared__ float Ws[FDIM * FDIM];
    int tid = threadIdx.x;
    #pragma unroll
    for (int i = 0; i < 4; ++i)
        ((float4*)Ws)[tid + 256 * i] = ((const float4*)Wm)[tid + 256 * i];
    mm_tile64<true>(ain, bias, 1, t, n, blockIdx.x, As, Ws);
}

// ===== combined dispatch: CSR-fill blocks (first) + matmul1 blocks =========
// Fill: unpartitioned grid-stride, 8 truly-independent atomics in flight.

__global__ __launch_bounds__(256) void k_mm_fill(
    const float* __restrict__ x, const float* __restrict__ W1,
    u32* __restrict__ t,
    const int* __restrict__ src, const int* __restrict__ dst,
    int* __restrict__ cnt, int* __restrict__ csr,
    int n, int E, int cap, int fill_blocks)
{
    __shared__ float As[64][FDIM + 1];
    __shared__ float Ws[FDIM * FDIM];

    if ((int)blockIdx.x < fill_blocks) {
        int stride = fill_blocks * 256;
        int e = blockIdx.x * 256 + threadIdx.x;
        for (; e + 7 * stride < E; e += 8 * stride) {
            int d[8], s[8], p[8];
            #pragma unroll
            for (int u = 0; u < 8; ++u)
                d[u] = __builtin_nontemporal_load(&dst[e + u * stride]);
            #pragma unroll
            for (int u = 0; u < 8; ++u)
                s[u] = __builtin_nontemporal_load(&src[e + u * stride]);
            #pragma unroll
            for (int u = 0; u < 8; ++u) p[u] = atomicAdd(&cnt[d[u]], 1);
            #pragma unroll
            for (int u = 0; u < 8; ++u)
                if (p[u] < cap) csr[(size_t)d[u] * cap + p[u]] = s[u];
        }
        for (; e < E; e += stride) {
            int d = dst[e];
            int p = atomicAdd(&cnt[d], 1);
            if (p < cap) csr[(size_t)d * cap + p] = src[e];
        }
        return;
    }

    int blk = blockIdx.x - fill_blocks;
    int tid = threadIdx.x;
    #pragma unroll
    for (int i = 0; i < 4; ++i)
        ((float4*)Ws)[tid + 256 * i] = ((const float4*)W1)[tid + 256 * i];
    mm_tile64<false>(x, nullptr, 0, t, n, blk, As, Ws);
}

// ======= gather-aggregate body for one node (16-lane group) ================
// Single fully-predicated 16-deep gather batch per csr chunk: lanes beyond
// cm contribute sv=0/dj=0 -> gather of row 0 (cache-hot) times zero. One
// latency wait per chunk instead of the 8/4/1 ladder's ~3.

__device__ __forceinline__ float4 agg_node(
    int i, const int* __restrict__ cnt, const int* __restrict__ csr,
    const u32* __restrict__ t, int cap, int li, int nbase)
{
    int deg = cnt[i];
    float di = rsqrtf((float)deg + 1.0f);
    int m = deg < cap ? deg : cap;

    u32 sp = t[(size_t)i * 16 + li];
    v2f s0 = __builtin_amdgcn_cvt_pk_f32_fp8(sp, false);
    v2f s1 = __builtin_amdgcn_cvt_pk_f32_fp8(sp, true);
    float4 A0 = make_float4(s0.x * di, s0.y * di, s1.x * di, s1.y * di);
    float4 A1 = make_float4(0.f, 0.f, 0.f, 0.f);
    float4 A2 = make_float4(0.f, 0.f, 0.f, 0.f);
    float4 A3 = make_float4(0.f, 0.f, 0.f, 0.f);

    const int* row = csr + (size_t)i * cap;

    for (int c0 = 0; c0 < m; c0 += 16) {
        int cm = m - c0; if (cm > 16) cm = 16;
        int sv = 0; float dvv = 0.f;
        if (li < cm) {
            sv = __builtin_nontemporal_load(&row[c0 + li]);
            dvv = rsqrtf((float)cnt[sv] + 1.0f);
        }
        int jv[16]; float dj[16]; u32 v[16];
        #pragma unroll
        for (int u = 0; u < 16; ++u) {
            jv[u] = __shfl(sv, nbase + u);
            dj[u] = __shfl(dvv, nbase + u);
        }
        #pragma unroll
        for (int u = 0; u < 16; ++u) v[u] = t[(size_t)jv[u] * 16 + li];
        #pragma unroll
        for (int u = 0; u < 16; ++u) {
            v2f x0 = __builtin_amdgcn_cvt_pk_f32_fp8(v[u], false);
            v2f x1 = __builtin_amdgcn_cvt_pk_f32_fp8(v[u], true);
            float4* Ap = (u & 3) == 0 ? &A0 : (u & 3) == 1 ? &A1 :
                         (u & 3) == 2 ? &A2 : &A3;
            Ap->x = fmaf(x0.x, dj[u], Ap->x);
            Ap->y = fmaf(x0.y, dj[u], Ap->y);
            Ap->z = fmaf(x1.x, dj[u], Ap->z);
            Ap->w = fmaf(x1.y, dj[u], Ap->w);
        }
    }

    float4 O;
    O.x = ((A0.x + A1.x) + (A2.x + A3.x)) * di;
    O.y = ((A0.y + A1.y) + (A2.y + A3.y)) * di;
    O.z = ((A0.z + A1.z) + (A2.z + A3.z)) * di;
    O.w = ((A0.w + A1.w) + (A2.w + A3.w)) * di;
    return O;
}

// == aggregate (layers 1-2): bf16 out, 4 nodes/wave, 16-lane groups ==

__global__ __launch_bounds__(256) void k_aggregate(
    const int* __restrict__ cnt, const int* __restrict__ csr,
    const u32* __restrict__ t, uint2* __restrict__ aggh, int n, int cap)
{
    int tid = threadIdx.x;
    long long gw = ((long long)blockIdx.x * 256 + tid) >> 6;
    int lane = tid & 63;
    int sub = lane >> 4;
    int li  = lane & 15;
    long long il = gw * 4 + sub;
    if (il >= n) return;
    int i = (int)il;

    float4 O = agg_node(i, cnt, csr, t, cap, li, sub << 4);
    uint2 pk;
    pk.x = ((u32)f2bf(O.x)) | (((u32)f2bf(O.y)) << 16);
    pk.y = ((u32)f2bf(O.z)) | (((u32)f2bf(O.w)) << 16);
    aggh[(size_t)i * 16 + li] = pk;
}

// == layer-3 aggregate fused with pool: block = (graph, part) ==

__global__ __launch_bounds__(256) void k_agg_pool(
    const int* __restrict__ cnt, const int* __restrict__ csr,
    const u32* __restrict__ t, const int* __restrict__ batch,
    float* __restrict__ partial, int n, int cap, int npart)
{
    int g = blockIdx.x / npart;
    int part = blockIdx.x - g * npart;
    int tid = threadIdx.x;

    int lo = 0, hi = n;
    while (lo < hi) { int mid = (lo + hi) >> 1; if (batch[mid] < g) lo = mid + 1; else hi = mid; }
    int start = lo;
    hi = n;
    while (lo < hi) { int mid = (lo + hi) >> 1; if (batch[mid] <= g) lo = mid + 1; else hi = mid; }
    int end = lo;

    int group = tid >> 4;     // 0..15
    int li = tid & 15;
    int lane = tid & 63;
    int nbase = (lane >> 4) << 4;

    float4 acc = make_float4(0.f, 0.f, 0.f, 0.f);
    for (int i = start + part * 16 + group; i < end; i += npart * 16) {
        float4 O = agg_node(i, cnt, csr, t, cap, li, nbase);
        acc.x += O.x; acc.y += O.y; acc.z += O.z; acc.w += O.w;
    }

    __shared__ float4 red[16][16];
    red[group][li] = acc;
    __syncthreads();
    if (tid < 16) {
        float4 s = make_float4(0.f, 0.f, 0.f, 0.f);
        #pragma unroll
        for (int q = 0; q < 16; ++q) {
            s.x += red[q][tid].x; s.y += red[q][tid].y;
            s.z += red[q][tid].z; s.w += red[q][tid].w;
        }
        ((float4*)partial)[((size_t)g * npart + part) * 16 + tid] = s;
    }
}

__global__ __launch_bounds__(64) void k_pool2(
    const float* __restrict__ partial, const int* __restrict__ batch,
    const float* __restrict__ b3, const float* __restrict__ Wlin,
    const float* __restrict__ blin, float* __restrict__ out,
    int n, int fout, int npart)
{
    int g = blockIdx.x;
    int tid = threadIdx.x;

    int lo = 0, hi = n;
    while (lo < hi) { int mid = (lo + hi) >> 1; if (batch[mid] < g) lo = mid + 1; else hi = mid; }
    int start = lo;
    hi = n;
    while (lo < hi) { int mid = (lo + hi) >> 1; if (batch[mid] <= g) lo = mid + 1; else hi = mid; }
    int cnt = lo - start;

    __shared__ float pooled[64];
    float v = 0.f;
    for (int p = 0; p < npart; ++p)
        v += partial[((size_t)g * npart + p) * 64 + tid];
    pooled[tid] = (cnt > 0) ? (v / (float)cnt + b3[tid]) : 0.f;
    __syncthreads();
    if (tid < fout) {
        float o = blin[tid];
        for (int k = 0; k < 64; ++k) o += pooled[k] * Wlin[k * fout + tid];
        out[(size_t)g * fout + tid] = o;
    }
}

// ================= launcher =================

extern "C" void kernel_launch(void* const* d_in, const int* in_sizes, int n_in,
                              void* d_out, int out_size, void* d_ws, size_t ws_size,
                              hipStream_t stream) {
    const float* x     = (const float*)d_in[0];
    const int*   ei    = (const int*)d_in[1];
    const int*   batch = (const int*)d_in[2];
    const float* W1 = (const float*)d_in[3];
    const float* b1 = (const float*)d_in[4];
    const float* W2 = (const float*)d_in[5];
    const float* b2 = (const float*)d_in[6];
    const float* W3 = (const float*)d_in[7];
    const float* b3 = (const float*)d_in[8];
    const float* Wl = (const float*)d_in[9];
    const float* bl = (const float*)d_in[10];

    int n = in_sizes[0] / 64;
    int E = in_sizes[1] / 2;
    int fout = in_sizes[10];
    int ngraphs = out_size / fout;

    const int* srcp = ei;
    const int* dstp = ei + E;

    const int npart = 16;

    // ws layout: agg bf16 | t fp8 | partial | cnt | csr
    float* ws   = (float*)d_ws;
    u32*   agg  = (u32*)ws;                          // n*32 u32 (bf16 pairs)
    u32*   t    = agg + (size_t)n * 32;              // n*16 u32 (fp8 rows)
    float* partial = (float*)(t + (size_t)n * 16);   // 64*16*64
    int* cnt    = (int*)(partial + 64 * npart * 64); // n
    int* csr    = cnt + n;                           // n*cap

    size_t fixed = (size_t)n * 32 * 4 + (size_t)n * 16 * 4 +
                   64 * npart * 64 * 4 + (size_t)n * 4;
    int cap = 64;
    while (cap > 32 && fixed + (size_t)n * cap * 4 > ws_size) cap -= 8;

    int nb_ag = (int)((((long long)(n + 3) / 4) * 64 + 255) / 256);
    int mm_blocks = (n + 63) / 64;
    int fill_blocks = 256;

    hipMemsetAsync(cnt, 0, (size_t)n * sizeof(int), stream);
    // CSR build (unpartitioned, 8-deep) + t1 = x @ W1 (fp8), one dispatch
    k_mm_fill<<<fill_blocks + mm_blocks, 256, 0, stream>>>(
        x, W1, t, srcp, dstp, cnt, csr, n, E, cap, fill_blocks);

    // layer 1 aggregate -> bf16 agg
    k_aggregate<<<nb_ag, 256, 0, stream>>>(cnt, csr, t, (uint2*)agg, n, cap);
    // layer 2
    k_matmul_h<<<mm_blocks, 256, 0, stream>>>((const u16*)agg, W2, b1, t, n);
    k_aggregate<<<nb_ag, 256, 0, stream>>>(cnt, csr, t, (uint2*)agg, n, cap);
    // layer 3
    k_matmul_h<<<mm_blocks, 256, 0, stream>>>((const u16*)agg, W3, b2, t, n);
    // layer-3 aggregate fused with pool partial-sum
    k_agg_pool<<<ngraphs * npart, 256, 0, stream>>>(cnt, csr, t, batch,
                                                    partial, n, cap, npart);
    k_pool2<<<ngraphs, 64, 0, stream>>>(partial, batch, b3, Wl, bl,
                                        (float*)d_out, n, fout, npart);
}